// Round 1
// baseline (468.109 us; speedup 1.0000x reference)
//
#include <hip/hip_runtime.h>
#include <hip/hip_bf16.h>

// Problem constants (fixed shapes from setup_inputs)
constexpr int   kC       = 19;
constexpr int   kHW      = 512 * 512;      // 262144 = 2^18
constexpr int   kHWShift = 18;
constexpr int   kN       = 8 * kHW;        // 2097152 pixels
constexpr int   kIgnore  = 255;
constexpr float kThresh  = 0.7f;
constexpr int   kMinKept = 100000;

constexpr int H1_BINS = 32768;   // top-16 bits of a non-negative float <= 0x7f80
constexpr int H2_BINS = 65536;   // low-16 bits
constexpr int kReduceBlocks = 1024;

// ---------------------------------------------------------------------------
// K1: main pass. Per pixel: CE(score0) -> 0.5*ce into d_out; for score1:
// loss = -log_softmax[t], pred = softmax[t] (or +inf if ignored); count valid.
// ---------------------------------------------------------------------------
__global__ __launch_bounds__(256) void k_main(const float* __restrict__ s0,
                                              const float* __restrict__ s1,
                                              const int* __restrict__ tgt,
                                              float* __restrict__ out,
                                              float* __restrict__ pred,
                                              float* __restrict__ loss,
                                              unsigned int* __restrict__ n_valid)
{
    int i = blockIdx.x * blockDim.x + threadIdx.x;
    bool mask = false;
    if (i < kN) {
        int t = tgt[i];
        mask = (t != kIgnore);
        int tt = mask ? t : 0;
        int b  = i >> kHWShift;
        int hw = i & (kHW - 1);
        const float* p0 = s0 + (size_t)b * kC * kHW + hw;
        const float* p1 = s1 + (size_t)b * kC * kHW + hw;
        float v0[kC], v1[kC];
        float m0 = -3.4e38f, m1 = -3.4e38f, st0 = 0.f, st1 = 0.f;
        #pragma unroll
        for (int c = 0; c < kC; ++c) {
            float a  = p0[(size_t)c * kHW];
            float bb = p1[(size_t)c * kHW];
            v0[c] = a; v1[c] = bb;
            m0 = fmaxf(m0, a); m1 = fmaxf(m1, bb);
            st0 = (c == tt) ? a  : st0;   // grab target-class logit (no runtime idx)
            st1 = (c == tt) ? bb : st1;
        }
        float sum0 = 0.f, sum1 = 0.f;
        #pragma unroll
        for (int c = 0; c < kC; ++c) {
            sum0 += __expf(v0[c] - m0);
            sum1 += __expf(v1[c] - m1);
        }
        float lse0 = m0 + __logf(sum0);
        float lse1 = m1 + __logf(sum1);
        out[i]  = mask ? 0.5f * (lse0 - st0) : 0.0f;
        loss[i] = mask ? (lse1 - st1) : 0.0f;
        pred[i] = mask ? __expf(st1 - lse1) : __uint_as_float(0x7f800000u); // +inf sorts last
    }
    unsigned long long bal = __ballot(mask);
    if ((threadIdx.x & 63) == 0)
        atomicAdd(n_valid, (unsigned int)__popcll(bal));
}

// ---------------------------------------------------------------------------
// K2: histogram of top-16 bits of pred's bit pattern. LDS-privatized
// (packed 2x u16 per u32, 64 KB) to avoid global atomic contention.
// grid=256 blocks -> <=8192 elems/block, so u16 bins can't overflow.
// ---------------------------------------------------------------------------
__global__ __launch_bounds__(256) void k_hist1(const float* __restrict__ pred,
                                               unsigned int* __restrict__ hist1)
{
    __shared__ unsigned int h[H1_BINS / 2];   // 16384 u32 = 64 KB
    for (int j = threadIdx.x; j < H1_BINS / 2; j += 256) h[j] = 0u;
    __syncthreads();
    int stride = gridDim.x * blockDim.x;
    for (int i = blockIdx.x * blockDim.x + threadIdx.x; i < kN; i += stride) {
        unsigned int bits = __float_as_uint(pred[i]);
        unsigned int b = bits >> 16;                       // <= 0x7f80
        atomicAdd(&h[b >> 1], (b & 1u) ? 0x10000u : 1u);
    }
    __syncthreads();
    for (int j = threadIdx.x; j < H1_BINS / 2; j += 256) {
        unsigned int v = h[j];
        if (v & 0xFFFFu) atomicAdd(&hist1[2 * j],     v & 0xFFFFu);
        if (v >> 16)     atomicAdd(&hist1[2 * j + 1], v >> 16);
    }
}

// ---------------------------------------------------------------------------
// K3: find bucket containing order statistic idx = clamp(min(MIN_KEPT, nv-1),0)
// ---------------------------------------------------------------------------
__global__ __launch_bounds__(256) void k_select1(const unsigned int* __restrict__ hist1,
                                                 const unsigned int* __restrict__ n_valid,
                                                 unsigned int* __restrict__ sel)
{
    __shared__ unsigned int sums[256];
    __shared__ unsigned int excl[256];
    int t = threadIdx.x;
    constexpr int PER = H1_BINS / 256;   // 128
    unsigned int s = 0;
    for (int j = 0; j < PER; ++j) s += hist1[t * PER + j];
    sums[t] = s;
    __syncthreads();
    if (t == 0) {
        unsigned int acc = 0;
        for (int j = 0; j < 256; ++j) { excl[j] = acc; acc += sums[j]; }
    }
    __syncthreads();
    long long idx = (long long)(*n_valid) - 1;
    if (idx > kMinKept) idx = kMinKept;
    if (idx < 0) idx = 0;
    unsigned int uidx = (unsigned int)idx;
    if (uidx >= excl[t] && uidx < excl[t] + sums[t]) {
        unsigned int rank = uidx - excl[t];
        for (int j = 0; j < PER; ++j) {
            unsigned int c = hist1[t * PER + j];
            if (rank < c) { sel[0] = (unsigned int)(t * PER + j); sel[1] = rank; break; }
            rank -= c;
        }
    }
}

// ---------------------------------------------------------------------------
// K4: refine — histogram low-16 bits of elements in the selected bucket.
// Few elements spread over 64K bins -> negligible atomic contention.
// ---------------------------------------------------------------------------
__global__ __launch_bounds__(256) void k_hist2(const float* __restrict__ pred,
                                               const unsigned int* __restrict__ sel,
                                               unsigned int* __restrict__ hist2)
{
    unsigned int bucket = sel[0];
    int stride = gridDim.x * blockDim.x;
    for (int i = blockIdx.x * blockDim.x + threadIdx.x; i < kN; i += stride) {
        unsigned int bits = __float_as_uint(pred[i]);
        if ((bits >> 16) == bucket) atomicAdd(&hist2[bits & 0xFFFFu], 1u);
    }
}

// ---------------------------------------------------------------------------
// K5: exact min_value from low-16 histogram; threshold = max(min_value, 0.7)
// ---------------------------------------------------------------------------
__global__ __launch_bounds__(256) void k_select2(const unsigned int* __restrict__ hist2,
                                                 const unsigned int* __restrict__ sel,
                                                 float* __restrict__ thr)
{
    __shared__ unsigned int sums[256];
    __shared__ unsigned int excl[256];
    int t = threadIdx.x;
    constexpr int PER = H2_BINS / 256;   // 256
    unsigned int s = 0;
    for (int j = 0; j < PER; ++j) s += hist2[t * PER + j];
    sums[t] = s;
    __syncthreads();
    if (t == 0) {
        unsigned int acc = 0;
        for (int j = 0; j < 256; ++j) { excl[j] = acc; acc += sums[j]; }
    }
    __syncthreads();
    unsigned int rank0 = sel[1];
    if (rank0 >= excl[t] && rank0 < excl[t] + sums[t]) {
        unsigned int rank = rank0 - excl[t];
        for (int j = 0; j < PER; ++j) {
            unsigned int c = hist2[t * PER + j];
            if (rank < c) {
                unsigned int bits = (sel[0] << 16) | (unsigned int)(t * PER + j);
                *thr = fmaxf(__uint_as_float(bits), kThresh);
                break;
            }
            rank -= c;
        }
    }
}

// ---------------------------------------------------------------------------
// K6: keep = pred < thr; partial num/den per block (fixed-order, deterministic)
// ---------------------------------------------------------------------------
__global__ __launch_bounds__(256) void k_reduce(const float* __restrict__ pred,
                                                const float* __restrict__ loss,
                                                const float* __restrict__ thr_p,
                                                float* __restrict__ pnum,
                                                unsigned int* __restrict__ pden)
{
    float thr = *thr_p;
    float num = 0.f; unsigned int den = 0;
    int stride = gridDim.x * blockDim.x;
    for (int i = blockIdx.x * blockDim.x + threadIdx.x; i < kN; i += stride) {
        float p = pred[i];                // +inf for ignored -> never < thr
        if (p < thr) { num += loss[i]; den += 1u; }
    }
    __shared__ float sn[256]; __shared__ unsigned int sd[256];
    int t = threadIdx.x;
    sn[t] = num; sd[t] = den; __syncthreads();
    for (int o = 128; o > 0; o >>= 1) {
        if (t < o) { sn[t] += sn[t + o]; sd[t] += sd[t + o]; }
        __syncthreads();
    }
    if (t == 0) { pnum[blockIdx.x] = sn[0]; pden[blockIdx.x] = sd[0]; }
}

// ---------------------------------------------------------------------------
// K7: final scalar: ohem_half = 0.5 * num/den  (fixed-order)
// ---------------------------------------------------------------------------
__global__ __launch_bounds__(256) void k_final_scalar(const float* __restrict__ pnum,
                                                      const unsigned int* __restrict__ pden,
                                                      float* __restrict__ ohem_half)
{
    int t = threadIdx.x;
    float num = 0.f; unsigned int den = 0;
    for (int j = t; j < kReduceBlocks; j += 256) { num += pnum[j]; den += pden[j]; }
    __shared__ float sn[256]; __shared__ unsigned int sd[256];
    sn[t] = num; sd[t] = den; __syncthreads();
    for (int o = 128; o > 0; o >>= 1) {
        if (t < o) { sn[t] += sn[t + o]; sd[t] += sd[t + o]; }
        __syncthreads();
    }
    if (t == 0) *ohem_half = 0.5f * (sn[0] / (float)sd[0]);
}

// ---------------------------------------------------------------------------
// K8: out[i] += 0.5*ohem  (d_out already holds 0.5*ce from K1)
// ---------------------------------------------------------------------------
__global__ __launch_bounds__(256) void k_add_scalar(float* __restrict__ out,
                                                    const float* __restrict__ ohem_half)
{
    int i = blockIdx.x * blockDim.x + threadIdx.x;
    if (i < kN) out[i] += *ohem_half;
}

extern "C" void kernel_launch(void* const* d_in, const int* in_sizes, int n_in,
                              void* d_out, int out_size, void* d_ws, size_t ws_size,
                              hipStream_t stream)
{
    const float* s0  = (const float*)d_in[0];
    const float* s1  = (const float*)d_in[1];
    const int*   tgt = (const int*)d_in[2];
    float* out = (float*)d_out;

    // ws layout
    char* ws = (char*)d_ws;
    float* pred = (float*)ws;                              // kN f32
    float* loss = (float*)(ws + (size_t)kN * 4);           // kN f32
    char*  A    = ws + (size_t)kN * 8;
    unsigned int* hist1   = (unsigned int*)A;                          // 128 KB
    unsigned int* hist2   = (unsigned int*)(A + (size_t)H1_BINS * 4);  // 256 KB
    unsigned int* n_valid = (unsigned int*)(A + (size_t)(H1_BINS + H2_BINS) * 4);
    unsigned int* sel     = n_valid + 1;                   // [bucket, rank]
    float* thr       = (float*)(sel + 2);
    float* ohem_half = thr + 1;
    float* pnum = (float*)(A + (size_t)(H1_BINS + H2_BINS) * 4 + 256);
    unsigned int* pden = (unsigned int*)(pnum + kReduceBlocks);

    // zero hist1+hist2+scalars (atomically accumulated each call)
    hipMemsetAsync(A, 0, (size_t)(H1_BINS + H2_BINS) * 4 + 256, stream);

    k_main<<<kN / 256, 256, 0, stream>>>(s0, s1, tgt, out, pred, loss, n_valid);
    k_hist1<<<256, 256, 0, stream>>>(pred, hist1);
    k_select1<<<1, 256, 0, stream>>>(hist1, n_valid, sel);
    k_hist2<<<2048, 256, 0, stream>>>(pred, sel, hist2);
    k_select2<<<1, 256, 0, stream>>>(hist2, sel, thr);
    k_reduce<<<kReduceBlocks, 256, 0, stream>>>(pred, loss, thr, pnum, pden);
    k_final_scalar<<<1, 256, 0, stream>>>(pnum, pden, ohem_half);
    k_add_scalar<<<kN / 256, 256, 0, stream>>>(out, ohem_half);
}

// Round 2
// 203.162 us; speedup vs baseline: 2.3041x; 2.3041x over previous
//
#include <hip/hip_runtime.h>
#include <hip/hip_bf16.h>

// Problem constants (fixed shapes from setup_inputs)
constexpr int   kC       = 19;
constexpr int   kHW      = 512 * 512;      // 262144 = 2^18
constexpr int   kHWShift = 18;
constexpr int   kN       = 8 * kHW;        // 2097152 pixels
constexpr int   kIgnore  = 255;
constexpr float kThresh  = 0.7f;
constexpr int   kMinKept = 100000;

constexpr int H1_BINS = 32768;   // top-16 bits of a non-negative float <= 0x7f80
constexpr int H2_BINS = 65536;   // low-16 bits
constexpr int kReduceBlocks = 1024;

// ---------------------------------------------------------------------------
// K1: main pass, 4 pixels/thread, online softmax (no per-channel arrays ->
// no scratch). Per pixel: out = 0.5*CE(score0); pred/loss from score1.
// ---------------------------------------------------------------------------
__global__ __launch_bounds__(256) void k_main(const float* __restrict__ s0,
                                              const float* __restrict__ s1,
                                              const int* __restrict__ tgt,
                                              float* __restrict__ out,
                                              float* __restrict__ pred,
                                              float* __restrict__ loss,
                                              unsigned int* __restrict__ n_valid)
{
    const int i4 = blockIdx.x * blockDim.x + threadIdx.x;   // vec-4 index
    const int i  = i4 * 4;                                  // pixel index
    const int b  = i >> kHWShift;
    const int hw = i & (kHW - 1);
    const float* p0 = s0 + (size_t)b * kC * kHW + hw;
    const float* p1 = s1 + (size_t)b * kC * kHW + hw;

    const int4 t4 = *(const int4*)(tgt + i);
    int  tt[4];
    bool mk[4];
    tt[0] = t4.x; tt[1] = t4.y; tt[2] = t4.z; tt[3] = t4.w;
    #pragma unroll
    for (int v = 0; v < 4; ++v) {
        mk[v] = (tt[v] != kIgnore);
        tt[v] = mk[v] ? tt[v] : 0;
    }

    float m0[4], sm0[4], st0[4];
    float m1[4], sm1[4], st1[4];
    #pragma unroll
    for (int v = 0; v < 4; ++v) {
        m0[v] = -3.4e38f; sm0[v] = 0.f; st0[v] = 0.f;
        m1[v] = -3.4e38f; sm1[v] = 0.f; st1[v] = 0.f;
    }

    #pragma unroll
    for (int c = 0; c < kC; ++c) {
        const float4 a4 = *(const float4*)(p0 + (size_t)c * kHW);
        const float4 b4 = *(const float4*)(p1 + (size_t)c * kHW);
        const float av[4] = {a4.x, a4.y, a4.z, a4.w};
        const float bv[4] = {b4.x, b4.y, b4.z, b4.w};
        #pragma unroll
        for (int v = 0; v < 4; ++v) {
            // online softmax for score0
            float mn = fmaxf(m0[v], av[v]);
            sm0[v] = sm0[v] * __expf(m0[v] - mn) + __expf(av[v] - mn);
            m0[v] = mn;
            st0[v] = (c == tt[v]) ? av[v] : st0[v];
            // online softmax for score1
            float mn1 = fmaxf(m1[v], bv[v]);
            sm1[v] = sm1[v] * __expf(m1[v] - mn1) + __expf(bv[v] - mn1);
            m1[v] = mn1;
            st1[v] = (c == tt[v]) ? bv[v] : st1[v];
        }
    }

    float4 o4, l4, p4;
    float ov[4], lv[4], pv[4];
    #pragma unroll
    for (int v = 0; v < 4; ++v) {
        const float lse0 = m0[v] + __logf(sm0[v]);
        const float lse1 = m1[v] + __logf(sm1[v]);
        ov[v] = mk[v] ? 0.5f * (lse0 - st0[v]) : 0.0f;
        lv[v] = mk[v] ? (lse1 - st1[v]) : 0.0f;
        pv[v] = mk[v] ? __expf(st1[v] - lse1) : __uint_as_float(0x7f800000u);
    }
    o4.x = ov[0]; o4.y = ov[1]; o4.z = ov[2]; o4.w = ov[3];
    l4.x = lv[0]; l4.y = lv[1]; l4.z = lv[2]; l4.w = lv[3];
    p4.x = pv[0]; p4.y = pv[1]; p4.z = pv[2]; p4.w = pv[3];
    *(float4*)(out  + i) = o4;
    *(float4*)(loss + i) = l4;
    *(float4*)(pred + i) = p4;

    // count valid pixels: lane-local 0..4, wave-reduce, one atomic per wave
    int cnt = (int)mk[0] + (int)mk[1] + (int)mk[2] + (int)mk[3];
    #pragma unroll
    for (int o = 32; o > 0; o >>= 1) cnt += __shfl_down(cnt, o, 64);
    if ((threadIdx.x & 63) == 0) atomicAdd(n_valid, (unsigned int)cnt);
}

// ---------------------------------------------------------------------------
// K2: histogram of top-16 bits of pred's bit pattern. LDS-privatized
// (packed 2x u16 per u32, 64 KB) to avoid global atomic contention.
// grid=256 blocks -> <=8192 elems/block, so u16 bins can't overflow.
// ---------------------------------------------------------------------------
__global__ __launch_bounds__(256) void k_hist1(const float* __restrict__ pred,
                                               unsigned int* __restrict__ hist1)
{
    __shared__ unsigned int h[H1_BINS / 2];   // 16384 u32 = 64 KB
    for (int j = threadIdx.x; j < H1_BINS / 2; j += 256) h[j] = 0u;
    __syncthreads();
    int stride = gridDim.x * blockDim.x;
    for (int i = blockIdx.x * blockDim.x + threadIdx.x; i < kN; i += stride) {
        unsigned int bits = __float_as_uint(pred[i]);
        unsigned int b = bits >> 16;                       // <= 0x7f80
        atomicAdd(&h[b >> 1], (b & 1u) ? 0x10000u : 1u);
    }
    __syncthreads();
    for (int j = threadIdx.x; j < H1_BINS / 2; j += 256) {
        unsigned int v = h[j];
        if (v & 0xFFFFu) atomicAdd(&hist1[2 * j],     v & 0xFFFFu);
        if (v >> 16)     atomicAdd(&hist1[2 * j + 1], v >> 16);
    }
}

// ---------------------------------------------------------------------------
// K3: find bucket containing order statistic idx = clamp(min(MIN_KEPT, nv-1),0)
// ---------------------------------------------------------------------------
__global__ __launch_bounds__(256) void k_select1(const unsigned int* __restrict__ hist1,
                                                 const unsigned int* __restrict__ n_valid,
                                                 unsigned int* __restrict__ sel)
{
    __shared__ unsigned int sums[256];
    __shared__ unsigned int excl[256];
    int t = threadIdx.x;
    constexpr int PER = H1_BINS / 256;   // 128
    unsigned int s = 0;
    for (int j = 0; j < PER; ++j) s += hist1[t * PER + j];
    sums[t] = s;
    __syncthreads();
    if (t == 0) {
        unsigned int acc = 0;
        for (int j = 0; j < 256; ++j) { excl[j] = acc; acc += sums[j]; }
    }
    __syncthreads();
    long long idx = (long long)(*n_valid) - 1;
    if (idx > kMinKept) idx = kMinKept;
    if (idx < 0) idx = 0;
    unsigned int uidx = (unsigned int)idx;
    if (uidx >= excl[t] && uidx < excl[t] + sums[t]) {
        unsigned int rank = uidx - excl[t];
        for (int j = 0; j < PER; ++j) {
            unsigned int c = hist1[t * PER + j];
            if (rank < c) { sel[0] = (unsigned int)(t * PER + j); sel[1] = rank; break; }
            rank -= c;
        }
    }
}

// ---------------------------------------------------------------------------
// K4: refine — histogram low-16 bits of elements in the selected bucket.
// ---------------------------------------------------------------------------
__global__ __launch_bounds__(256) void k_hist2(const float* __restrict__ pred,
                                               const unsigned int* __restrict__ sel,
                                               unsigned int* __restrict__ hist2)
{
    unsigned int bucket = sel[0];
    int stride = gridDim.x * blockDim.x;
    for (int i = blockIdx.x * blockDim.x + threadIdx.x; i < kN; i += stride) {
        unsigned int bits = __float_as_uint(pred[i]);
        if ((bits >> 16) == bucket) atomicAdd(&hist2[bits & 0xFFFFu], 1u);
    }
}

// ---------------------------------------------------------------------------
// K5: exact min_value from low-16 histogram; threshold = max(min_value, 0.7)
// ---------------------------------------------------------------------------
__global__ __launch_bounds__(256) void k_select2(const unsigned int* __restrict__ hist2,
                                                 const unsigned int* __restrict__ sel,
                                                 float* __restrict__ thr)
{
    __shared__ unsigned int sums[256];
    __shared__ unsigned int excl[256];
    int t = threadIdx.x;
    constexpr int PER = H2_BINS / 256;   // 256
    unsigned int s = 0;
    for (int j = 0; j < PER; ++j) s += hist2[t * PER + j];
    sums[t] = s;
    __syncthreads();
    if (t == 0) {
        unsigned int acc = 0;
        for (int j = 0; j < 256; ++j) { excl[j] = acc; acc += sums[j]; }
    }
    __syncthreads();
    unsigned int rank0 = sel[1];
    if (rank0 >= excl[t] && rank0 < excl[t] + sums[t]) {
        unsigned int rank = rank0 - excl[t];
        for (int j = 0; j < PER; ++j) {
            unsigned int c = hist2[t * PER + j];
            if (rank < c) {
                unsigned int bits = (sel[0] << 16) | (unsigned int)(t * PER + j);
                *thr = fmaxf(__uint_as_float(bits), kThresh);
                break;
            }
            rank -= c;
        }
    }
}

// ---------------------------------------------------------------------------
// K6: keep = pred < thr; partial num/den per block (fixed-order, deterministic)
// ---------------------------------------------------------------------------
__global__ __launch_bounds__(256) void k_reduce(const float* __restrict__ pred,
                                                const float* __restrict__ loss,
                                                const float* __restrict__ thr_p,
                                                float* __restrict__ pnum,
                                                unsigned int* __restrict__ pden)
{
    float thr = *thr_p;
    float num = 0.f; unsigned int den = 0;
    int stride = gridDim.x * blockDim.x;
    for (int i = blockIdx.x * blockDim.x + threadIdx.x; i < kN; i += stride) {
        float p = pred[i];                // +inf for ignored -> never < thr
        if (p < thr) { num += loss[i]; den += 1u; }
    }
    __shared__ float sn[256]; __shared__ unsigned int sd[256];
    int t = threadIdx.x;
    sn[t] = num; sd[t] = den; __syncthreads();
    for (int o = 128; o > 0; o >>= 1) {
        if (t < o) { sn[t] += sn[t + o]; sd[t] += sd[t + o]; }
        __syncthreads();
    }
    if (t == 0) { pnum[blockIdx.x] = sn[0]; pden[blockIdx.x] = sd[0]; }
}

// ---------------------------------------------------------------------------
// K7: final scalar: ohem_half = 0.5 * num/den  (fixed-order)
// ---------------------------------------------------------------------------
__global__ __launch_bounds__(256) void k_final_scalar(const float* __restrict__ pnum,
                                                      const unsigned int* __restrict__ pden,
                                                      float* __restrict__ ohem_half)
{
    int t = threadIdx.x;
    float num = 0.f; unsigned int den = 0;
    for (int j = t; j < kReduceBlocks; j += 256) { num += pnum[j]; den += pden[j]; }
    __shared__ float sn[256]; __shared__ unsigned int sd[256];
    sn[t] = num; sd[t] = den; __syncthreads();
    for (int o = 128; o > 0; o >>= 1) {
        if (t < o) { sn[t] += sn[t + o]; sd[t] += sd[t + o]; }
        __syncthreads();
    }
    if (t == 0) *ohem_half = 0.5f * (sn[0] / (float)sd[0]);
}

// ---------------------------------------------------------------------------
// K8: out[i] += 0.5*ohem  (d_out already holds 0.5*ce from K1)
// ---------------------------------------------------------------------------
__global__ __launch_bounds__(256) void k_add_scalar(float* __restrict__ out,
                                                    const float* __restrict__ ohem_half)
{
    float a = *ohem_half;
    int i = (blockIdx.x * blockDim.x + threadIdx.x) * 4;
    float4 o = *(float4*)(out + i);
    o.x += a; o.y += a; o.z += a; o.w += a;
    *(float4*)(out + i) = o;
}

extern "C" void kernel_launch(void* const* d_in, const int* in_sizes, int n_in,
                              void* d_out, int out_size, void* d_ws, size_t ws_size,
                              hipStream_t stream)
{
    const float* s0  = (const float*)d_in[0];
    const float* s1  = (const float*)d_in[1];
    const int*   tgt = (const int*)d_in[2];
    float* out = (float*)d_out;

    // ws layout
    char* ws = (char*)d_ws;
    float* pred = (float*)ws;                              // kN f32
    float* loss = (float*)(ws + (size_t)kN * 4);           // kN f32
    char*  A    = ws + (size_t)kN * 8;
    unsigned int* hist1   = (unsigned int*)A;                          // 128 KB
    unsigned int* hist2   = (unsigned int*)(A + (size_t)H1_BINS * 4);  // 256 KB
    unsigned int* n_valid = (unsigned int*)(A + (size_t)(H1_BINS + H2_BINS) * 4);
    unsigned int* sel     = n_valid + 1;                   // [bucket, rank]
    float* thr       = (float*)(sel + 2);
    float* ohem_half = thr + 1;
    float* pnum = (float*)(A + (size_t)(H1_BINS + H2_BINS) * 4 + 256);
    unsigned int* pden = (unsigned int*)(pnum + kReduceBlocks);

    // zero hist1+hist2+scalars (atomically accumulated each call)
    hipMemsetAsync(A, 0, (size_t)(H1_BINS + H2_BINS) * 4 + 256, stream);

    k_main<<<kN / 4 / 256, 256, 0, stream>>>(s0, s1, tgt, out, pred, loss, n_valid);
    k_hist1<<<256, 256, 0, stream>>>(pred, hist1);
    k_select1<<<1, 256, 0, stream>>>(hist1, n_valid, sel);
    k_hist2<<<2048, 256, 0, stream>>>(pred, sel, hist2);
    k_select2<<<1, 256, 0, stream>>>(hist2, sel, thr);
    k_reduce<<<kReduceBlocks, 256, 0, stream>>>(pred, loss, thr, pnum, pden);
    k_final_scalar<<<1, 256, 0, stream>>>(pnum, pden, ohem_half);
    k_add_scalar<<<kN / 4 / 256, 256, 0, stream>>>(out, ohem_half);
}